// Round 1
// baseline (14115.710 us; speedup 1.0000x reference)
//
#include <hip/hip_runtime.h>
#include <math.h>

#define S_LEN   1023
#define BATCH_N 4
#define DMODEL  512
#define NHEAD   8
#define DHEAD   64
#define DINNER  2048
#define NLAYER  4
#define RAWLEN  8192
#define POOLW   8
#define KERNW   9
#define RLEN    (2*S_LEN-1)   /* 2045 */
#define MROWS   (S_LEN*BATCH_N) /* 4092 */

// ---------------- conv + relu + pool8 -> core (S, B, D) ----------------
__global__ __launch_bounds__(512) void conv_pool_kernel(
    const float* __restrict__ sig, const float* __restrict__ cw,
    const float* __restrict__ cb, float* __restrict__ core)
{
    int s = blockIdx.x;   // 0..1022
    int b = blockIdx.y;   // 0..3
    int d = threadIdx.x;  // 0..511
    __shared__ float sseg[POOLW + KERNW - 1]; // 16 signal samples
    if (d < POOLW + KERNW - 1) sseg[d] = sig[b*RAWLEN + s*POOLW + d];
    __syncthreads();
    float w[KERNW];
#pragma unroll
    for (int k = 0; k < KERNW; k++) w[k] = cw[k*DMODEL + d];
    float bias = cb[d];
    float acc = 0.f;
#pragma unroll
    for (int p = 0; p < POOLW; p++) {
        float c = bias;
#pragma unroll
        for (int k = 0; k < KERNW; k++) c = fmaf(sseg[p+k], w[k], c);
        acc += fmaxf(c, 0.f);
    }
    core[(s*BATCH_N + b)*DMODEL + d] = acc * (1.0f/POOLW);
}

// ---------------- positional embedding table (2S-1, D) ----------------
__global__ __launch_bounds__(512) void posemb_kernel(float* __restrict__ pe)
{
    int j = blockIdx.x;   // 0..2044
    int d = threadIdx.x;  // 0..511
    float pos = (float)(S_LEN - 1 - j);
    int i = (d < 256) ? d : d - 256;
    float invf = powf(10000.0f, -(float)i * (1.0f/256.0f));
    float a = pos * invf;
    pe[j*DMODEL + d] = (d < 256) ? sinf(a) : cosf(a);
}

// ---------------- tiled f32 GEMM: C (= or +=) op(A@B + bias) ----------------
// A: MxK row-major, B: KxN row-major, C: MxN row-major. N,K multiples of 16; M guarded.
template<bool HAS_BIAS, bool RELU, bool ACCUM>
__global__ __launch_bounds__(256) void gemm_f32(
    const float* __restrict__ A, const float* __restrict__ B,
    const float* __restrict__ bias, float* __restrict__ C,
    int M, int N, int K)
{
    const int BM = 64, BN = 64, BK = 16;
    __shared__ float As[BK][BM + 1];
    __shared__ float Bs[BK][BN];
    int bm = blockIdx.y * BM;
    int bn = blockIdx.x * BN;
    int tid = threadIdx.x;
    int tx = tid & 15;       // N direction, 4 cols each
    int ty = tid >> 4;       // M direction, 4 rows each
    float acc[4][4] = {};
    for (int k0 = 0; k0 < K; k0 += BK) {
        // A tile load: row = tid/4 (64 rows), 4 contiguous k per thread
        {
            int row = tid >> 2;
            int kq  = (tid & 3) * 4;
            float4 v = make_float4(0.f, 0.f, 0.f, 0.f);
            if (bm + row < M)
                v = *reinterpret_cast<const float4*>(&A[(size_t)(bm + row)*K + k0 + kq]);
            As[kq + 0][row] = v.x;
            As[kq + 1][row] = v.y;
            As[kq + 2][row] = v.z;
            As[kq + 3][row] = v.w;
        }
        // B tile load: kk = tid/16 (16 rows), 4 contiguous n per thread
        {
            int kk = tid >> 4;
            int nq = (tid & 15) * 4;
            float4 v = *reinterpret_cast<const float4*>(&B[(size_t)(k0 + kk)*N + bn + nq]);
            *reinterpret_cast<float4*>(&Bs[kk][nq]) = v;
        }
        __syncthreads();
#pragma unroll
        for (int kk = 0; kk < BK; kk++) {
            float a[4], bb[4];
#pragma unroll
            for (int r = 0; r < 4; r++) a[r] = As[kk][ty*4 + r];
#pragma unroll
            for (int c = 0; c < 4; c++) bb[c] = Bs[kk][tx*4 + c];
#pragma unroll
            for (int r = 0; r < 4; r++)
#pragma unroll
                for (int c = 0; c < 4; c++)
                    acc[r][c] = fmaf(a[r], bb[c], acc[r][c]);
        }
        __syncthreads();
    }
#pragma unroll
    for (int r = 0; r < 4; r++) {
        int row = bm + ty*4 + r;
        if (row >= M) continue;
#pragma unroll
        for (int c = 0; c < 4; c++) {
            int col = bn + tx*4 + c;
            float v = acc[r][c];
            if (HAS_BIAS) v += bias[col];
            if (RELU) v = fmaxf(v, 0.f);
            if (ACCUM) C[(size_t)row*N + col] += v;
            else       C[(size_t)row*N + col] = v;
        }
    }
}

// ---------------- fused attention row: scores -> softmax -> PV ----------------
// one block per (query i, batch b, head n)
__global__ __launch_bounds__(256) void attn_kernel(
    const float* __restrict__ heads,   // (S, B, 3*512)
    const float* __restrict__ rk,      // (2S-1, 512)
    const float* __restrict__ rwb,     // (8, 64)
    const float* __restrict__ rrb,     // (8, 64)
    float* __restrict__ attn_vec)      // (S, B, 512)
{
    int i  = blockIdx.x;          // 0..1022
    int bn = blockIdx.y;          // 0..31
    int b = bn >> 3, n = bn & 7;
    int tid  = threadIdx.x;
    int lane = tid & 63;
    int wid  = tid >> 6;          // 4 waves

    __shared__ float qv[DHEAD], qr[DHEAD];
    __shared__ float sc[S_LEN];
    __shared__ float red[4*DHEAD];
    __shared__ float rbuf[4], rbuf2[4];

    if (tid < DHEAD) {
        float qd = heads[(size_t)(i*BATCH_N + b)*(3*DMODEL) + n*DHEAD + tid];
        qv[tid] = qd + rwb[n*DHEAD + tid];
        qr[tid] = qd + rrb[n*DHEAD + tid];
    }
    __syncthreads();
    float qvl = qv[lane], qrl = qr[lane];

    // scores: each wave computes one j per iteration (coalesced 64-wide dot)
    for (int j = wid; j < S_LEN; j += 4) {
        float kv = heads[(size_t)(j*BATCH_N + b)*(3*DMODEL) + DMODEL + n*DHEAD + lane];
        float rv = rk[(size_t)(S_LEN - 1 - i + j)*DMODEL + n*DHEAD + lane];
        float p = qvl*kv + qrl*rv;
#pragma unroll
        for (int off = 32; off; off >>= 1) p += __shfl_xor(p, off);
        if (lane == 0) sc[j] = p * 0.125f;
    }
    __syncthreads();

    // block max
    float m = -1e30f;
    for (int j = tid; j < S_LEN; j += 256) m = fmaxf(m, sc[j]);
#pragma unroll
    for (int off = 32; off; off >>= 1) m = fmaxf(m, __shfl_xor(m, off));
    if (lane == 0) rbuf[wid] = m;
    __syncthreads();
    m = fmaxf(fmaxf(rbuf[0], rbuf[1]), fmaxf(rbuf[2], rbuf[3]));

    // exp + block sum
    float ssum = 0.f;
    for (int j = tid; j < S_LEN; j += 256) {
        float e = expf(sc[j] - m);
        sc[j] = e;
        ssum += e;
    }
#pragma unroll
    for (int off = 32; off; off >>= 1) ssum += __shfl_xor(ssum, off);
    if (lane == 0) rbuf2[wid] = ssum;
    __syncthreads();
    float inv = 1.0f / (rbuf2[0] + rbuf2[1] + rbuf2[2] + rbuf2[3]);

    // PV: lane = d, coalesced v reads, 4 waves split j range
    float acc = 0.f;
    for (int j = wid; j < S_LEN; j += 4)
        acc += sc[j] * heads[(size_t)(j*BATCH_N + b)*(3*DMODEL) + 2*DMODEL + n*DHEAD + lane];
    red[wid*DHEAD + lane] = acc;
    __syncthreads();
    if (tid < DHEAD) {
        float o = (red[tid] + red[DHEAD+tid] + red[2*DHEAD+tid] + red[3*DHEAD+tid]) * inv;
        attn_vec[(size_t)(i*BATCH_N + b)*DMODEL + n*DHEAD + tid] = o;
    }
}

// ---------------- final classifier: out(b,c) = core[S-1,b,:] . fc_w[:,c] + fc_b ----------------
__global__ __launch_bounds__(64) void final_kernel(
    const float* __restrict__ core, const float* __restrict__ fcw,
    const float* __restrict__ fcb, float* __restrict__ out)
{
    int idx = blockIdx.x;       // 0..39
    int b = idx / 10, c = idx % 10;
    int lane = threadIdx.x;
    const float* row = &core[(size_t)((S_LEN-1)*BATCH_N + b)*DMODEL];
    float acc = 0.f;
    for (int d = lane; d < DMODEL; d += 64)
        acc = fmaf(row[d], fcw[d*10 + c], acc);
#pragma unroll
    for (int off = 32; off; off >>= 1) acc += __shfl_xor(acc, off);
    if (lane == 0) out[b*10 + c] = acc + fcb[c];
}

extern "C" void kernel_launch(void* const* d_in, const int* in_sizes, int n_in,
                              void* d_out, int out_size, void* d_ws, size_t ws_size,
                              hipStream_t stream)
{
    const float* sig   = (const float*)d_in[0];
    const float* cw    = (const float*)d_in[1];
    const float* cb    = (const float*)d_in[2];
    const float* qkv_w = (const float*)d_in[3];
    const float* r_w   = (const float*)d_in[4];
    const float* o_w   = (const float*)d_in[5];
    const float* ff1_w = (const float*)d_in[6];
    const float* ff1_b = (const float*)d_in[7];
    const float* ff2_w = (const float*)d_in[8];
    const float* ff2_b = (const float*)d_in[9];
    const float* rwb   = (const float*)d_in[10];
    const float* rrb   = (const float*)d_in[11];
    const float* fcw   = (const float*)d_in[12];
    const float* fcb   = (const float*)d_in[13];
    float* out = (float*)d_out;

    float* ws   = (float*)d_ws;
    float* core = ws;                          // 4092*512
    float* pe   = core + (size_t)MROWS*DMODEL; // 2045*512
    float* rk   = pe   + (size_t)RLEN*DMODEL;  // 2045*512
    float* av   = rk   + (size_t)RLEN*DMODEL;  // 4092*512
    float* big  = av   + (size_t)MROWS*DMODEL; // 4092*2048 (heads / ffn hidden)

    conv_pool_kernel<<<dim3(S_LEN, BATCH_N), 512, 0, stream>>>(sig, cw, cb, core);
    posemb_kernel<<<RLEN, 512, 0, stream>>>(pe);

    for (int l = 0; l < NLAYER; l++) {
        const float* qkvw_l = qkv_w + (size_t)l*DMODEL*(3*DMODEL);
        const float* rw_l   = r_w   + (size_t)l*DMODEL*DMODEL;
        const float* ow_l   = o_w   + (size_t)l*DMODEL*DMODEL;
        const float* f1w_l  = ff1_w + (size_t)l*DMODEL*DINNER;
        const float* f1b_l  = ff1_b + (size_t)l*DINNER;
        const float* f2w_l  = ff2_w + (size_t)l*DINNER*DMODEL;
        const float* f2b_l  = ff2_b + (size_t)l*DMODEL;

        // heads = core @ qkv_w[l]   (4092 x 1536)
        gemm_f32<false,false,false><<<dim3((3*DMODEL)/64, (MROWS+63)/64), 256, 0, stream>>>(
            core, qkvw_l, nullptr, big, MROWS, 3*DMODEL, DMODEL);
        // rk = pos_emb @ r_w[l]     (2045 x 512)
        gemm_f32<false,false,false><<<dim3(DMODEL/64, (RLEN+63)/64), 256, 0, stream>>>(
            pe, rw_l, nullptr, rk, RLEN, DMODEL, DMODEL);
        // fused attention
        attn_kernel<<<dim3(S_LEN, BATCH_N*NHEAD), 256, 0, stream>>>(big, rk, rwb, rrb, av);
        // core += attn_vec @ o_w[l]
        gemm_f32<false,false,true><<<dim3(DMODEL/64, (MROWS+63)/64), 256, 0, stream>>>(
            av, ow_l, nullptr, core, MROWS, DMODEL, DMODEL);
        // big = relu(core @ ff1_w + ff1_b)   (4092 x 2048)
        gemm_f32<true,true,false><<<dim3(DINNER/64, (MROWS+63)/64), 256, 0, stream>>>(
            core, f1w_l, f1b_l, big, MROWS, DINNER, DMODEL);
        // core += big @ ff2_w + ff2_b
        gemm_f32<true,false,true><<<dim3(DMODEL/64, (MROWS+63)/64), 256, 0, stream>>>(
            big, f2w_l, f2b_l, core, MROWS, DMODEL, DINNER);
    }

    final_kernel<<<40, 64, 0, stream>>>(core, fcw, fcb, out);
}

// Round 2
// 3890.578 us; speedup vs baseline: 3.6282x; 3.6282x over previous
//
#include <hip/hip_runtime.h>
#include <math.h>

#define S_LEN   1023
#define BATCH_N 4
#define DMODEL  512
#define NHEAD   8
#define DHEAD   64
#define DINNER  2048
#define NLAYER  4
#define RAWLEN  8192
#define POOLW   8
#define KERNW   9
#define RLEN    (2*S_LEN-1)   /* 2045 */
#define MROWS   (S_LEN*BATCH_N) /* 4092 */

// attention tiling
#define TI 48
#define TJ 32
#define RKROWS 80   /* TI+TJ-1 = 79, padded to 80 */
#define PADQ 68     /* row stride (floats) for Qs/Ks/Vs/rks */
#define PADP 36     /* row stride for P */

// ---------------- conv + relu + pool8 -> core (S, B, D) ----------------
__global__ __launch_bounds__(512) void conv_pool_kernel(
    const float* __restrict__ sig, const float* __restrict__ cw,
    const float* __restrict__ cb, float* __restrict__ core)
{
    int s = blockIdx.x;   // 0..1022
    int b = blockIdx.y;   // 0..3
    int d = threadIdx.x;  // 0..511
    __shared__ float sseg[POOLW + KERNW - 1]; // 16 signal samples
    if (d < POOLW + KERNW - 1) sseg[d] = sig[b*RAWLEN + s*POOLW + d];
    __syncthreads();
    float w[KERNW];
#pragma unroll
    for (int k = 0; k < KERNW; k++) w[k] = cw[k*DMODEL + d];
    float bias = cb[d];
    float acc = 0.f;
#pragma unroll
    for (int p = 0; p < POOLW; p++) {
        float c = bias;
#pragma unroll
        for (int k = 0; k < KERNW; k++) c = fmaf(sseg[p+k], w[k], c);
        acc += fmaxf(c, 0.f);
    }
    core[(s*BATCH_N + b)*DMODEL + d] = acc * (1.0f/POOLW);
}

// ---------------- positional embedding table (2S-1, D) ----------------
__global__ __launch_bounds__(512) void posemb_kernel(float* __restrict__ pe)
{
    int j = blockIdx.x;   // 0..2044
    int d = threadIdx.x;  // 0..511
    float pos = (float)(S_LEN - 1 - j);
    int i = (d < 256) ? d : d - 256;
    float invf = powf(10000.0f, -(float)i * (1.0f/256.0f));
    float a = pos * invf;
    pe[j*DMODEL + d] = (d < 256) ? sinf(a) : cosf(a);
}

// ---------------- tiled f32 GEMM: C (= or +=) op(A@B + bias) ----------------
template<bool HAS_BIAS, bool RELU, bool ACCUM>
__global__ __launch_bounds__(256) void gemm_f32(
    const float* __restrict__ A, const float* __restrict__ B,
    const float* __restrict__ bias, float* __restrict__ C,
    int M, int N, int K)
{
    const int BM = 64, BN = 64, BK = 16;
    __shared__ float As[BK][BM + 1];
    __shared__ float Bs[BK][BN];
    int bm = blockIdx.y * BM;
    int bn = blockIdx.x * BN;
    int tid = threadIdx.x;
    int tx = tid & 15;
    int ty = tid >> 4;
    float acc[4][4] = {};
    for (int k0 = 0; k0 < K; k0 += BK) {
        {
            int row = tid >> 2;
            int kq  = (tid & 3) * 4;
            float4 v = make_float4(0.f, 0.f, 0.f, 0.f);
            if (bm + row < M)
                v = *reinterpret_cast<const float4*>(&A[(size_t)(bm + row)*K + k0 + kq]);
            As[kq + 0][row] = v.x;
            As[kq + 1][row] = v.y;
            As[kq + 2][row] = v.z;
            As[kq + 3][row] = v.w;
        }
        {
            int kk = tid >> 4;
            int nq = (tid & 15) * 4;
            float4 v = *reinterpret_cast<const float4*>(&B[(size_t)(k0 + kk)*N + bn + nq]);
            *reinterpret_cast<float4*>(&Bs[kk][nq]) = v;
        }
        __syncthreads();
#pragma unroll
        for (int kk = 0; kk < BK; kk++) {
            float a[4], bb[4];
#pragma unroll
            for (int r = 0; r < 4; r++) a[r] = As[kk][ty*4 + r];
#pragma unroll
            for (int c = 0; c < 4; c++) bb[c] = Bs[kk][tx*4 + c];
#pragma unroll
            for (int r = 0; r < 4; r++)
#pragma unroll
                for (int c = 0; c < 4; c++)
                    acc[r][c] = fmaf(a[r], bb[c], acc[r][c]);
        }
        __syncthreads();
    }
#pragma unroll
    for (int r = 0; r < 4; r++) {
        int row = bm + ty*4 + r;
        if (row >= M) continue;
#pragma unroll
        for (int c = 0; c < 4; c++) {
            int col = bn + tx*4 + c;
            float v = acc[r][c];
            if (HAS_BIAS) v += bias[col];
            if (RELU) v = fmaxf(v, 0.f);
            if (ACCUM) C[(size_t)row*N + col] += v;
            else       C[(size_t)row*N + col] = v;
        }
    }
}

// ---------------- c1[bn][j] = rwb[n] . K[j,b,n,:] ----------------
__global__ __launch_bounds__(256) void c1_kernel(
    const float* __restrict__ heads, const float* __restrict__ rwb,
    float* __restrict__ c1)
{
    int bn = blockIdx.y; int b = bn >> 3, n = bn & 7;
    int wid = threadIdx.x >> 6, lane = threadIdx.x & 63;
    int j = blockIdx.x * 4 + wid;
    if (j >= S_LEN) return;
    float p = rwb[n*DHEAD + lane] *
              heads[(size_t)(j*BATCH_N + b)*(3*DMODEL) + DMODEL + n*DHEAD + lane];
#pragma unroll
    for (int off = 32; off; off >>= 1) p += __shfl_xor(p, off);
    if (lane == 0) c1[bn*S_LEN + j] = p;
}

// ---------------- c2[n][jr] = rrb[n] . rk[jr,n,:] ----------------
__global__ __launch_bounds__(256) void c2_kernel(
    const float* __restrict__ rk, const float* __restrict__ rrb,
    float* __restrict__ c2)
{
    int n = blockIdx.y;
    int wid = threadIdx.x >> 6, lane = threadIdx.x & 63;
    int j = blockIdx.x * 4 + wid;
    if (j >= RLEN) return;
    float p = rrb[n*DHEAD + lane] * rk[(size_t)j*DMODEL + n*DHEAD + lane];
#pragma unroll
    for (int off = 32; off; off >>= 1) p += __shfl_xor(p, off);
    if (lane == 0) c2[n*RLEN + j] = p;
}

// ---------------- flash attention: TI queries x TJ keys per step ----------------
// block = (i-tile, bn); scores = (q.K + q.rk + c1[j] + c2[jr]) * 0.125
__global__ __launch_bounds__(256) void attn_flash_kernel(
    const float* __restrict__ heads,   // (S, B, 1536)
    const float* __restrict__ rk,      // (2S-1, 512)
    const float* __restrict__ c1,      // (32, S)
    const float* __restrict__ c2,      // (8, 2S-1)
    float* __restrict__ av)            // (S, B, 512)
{
    int i0 = blockIdx.x * TI;
    int bn = blockIdx.y; int b = bn >> 3, n = bn & 7;
    int tid = threadIdx.x;

    __shared__ float Qs[TI][PADQ];
    __shared__ float Ks[TJ][PADQ];
    __shared__ float Vs[TJ][PADQ];
    __shared__ float rks[RKROWS][PADQ];
    __shared__ float Ps[TI][PADP];
    __shared__ float mbuf[TI], lbuf[TI], fbuf[TI];
    __shared__ float c1s[TJ];
    __shared__ float c2s[RKROWS];

    // stage Q (raw q, biases folded into c1/c2)
    for (int p = tid; p < TI*16; p += 256) {
        int r = p >> 4, fq = (p & 15) * 4;
        int gi = i0 + r;
        float4 v = make_float4(0.f, 0.f, 0.f, 0.f);
        if (gi < S_LEN)
            v = *reinterpret_cast<const float4*>(
                &heads[(size_t)(gi*BATCH_N + b)*(3*DMODEL) + n*DHEAD + fq]);
        *reinterpret_cast<float4*>(&Qs[r][fq]) = v;
    }
    if (tid < TI) { mbuf[tid] = -1e30f; lbuf[tid] = 0.f; }

    int iy = tid >> 4;          // score: 16 groups of 3 i's
    int jx = tid & 15;          // score: j = jx and jx+16
    int py = tid >> 4;          // PV: 3 i's
    int px = tid & 15;          // PV: d-quad
    float o[3][4] = {};

    for (int j0 = 0; j0 < S_LEN; j0 += TJ) {
        int base = (S_LEN-1) - i0 - (TI-1) + j0;  // rk global row of local row 0
        __syncthreads();
        // stage K, V
        for (int p = tid; p < TJ*16; p += 256) {
            int r = p >> 4, fq = (p & 15) * 4;
            int gj = j0 + r;
            float4 kv = make_float4(0.f,0.f,0.f,0.f), vv = kv;
            if (gj < S_LEN) {
                size_t rowb = (size_t)(gj*BATCH_N + b)*(3*DMODEL) + n*DHEAD + fq;
                kv = *reinterpret_cast<const float4*>(&heads[rowb + DMODEL]);
                vv = *reinterpret_cast<const float4*>(&heads[rowb + 2*DMODEL]);
            }
            *reinterpret_cast<float4*>(&Ks[r][fq]) = kv;
            *reinterpret_cast<float4*>(&Vs[r][fq]) = vv;
        }
        // stage rk window
        for (int p = tid; p < RKROWS*16; p += 256) {
            int r = p >> 4, fq = (p & 15) * 4;
            int gr = base + r;
            gr = gr < 0 ? 0 : (gr > RLEN-1 ? RLEN-1 : gr);
            *reinterpret_cast<float4*>(&rks[r][fq]) =
                *reinterpret_cast<const float4*>(&rk[(size_t)gr*DMODEL + n*DHEAD + fq]);
        }
        if (tid < TJ) {
            int gj = j0 + tid;
            c1s[tid] = (gj < S_LEN) ? c1[bn*S_LEN + gj] : 0.f;
        } else if (tid < TJ + RKROWS) {
            int r = tid - TJ;
            int gr = base + r;
            gr = gr < 0 ? 0 : (gr > RLEN-1 ? RLEN-1 : gr);
            c2s[r] = c2[n*RLEN + gr];
        }
        __syncthreads();

        // scores: thread -> (3 i's) x (2 j's: jx, jx+16)
        float acc[3][2] = {};
#pragma unroll 4
        for (int dq = 0; dq < 64; dq += 4) {
            float4 k0 = *reinterpret_cast<const float4*>(&Ks[jx][dq]);
            float4 k1 = *reinterpret_cast<const float4*>(&Ks[jx+16][dq]);
#pragma unroll
            for (int r = 0; r < 3; r++) {
                int ii = iy*3 + r;
                float4 q = *reinterpret_cast<const float4*>(&Qs[ii][dq]);
                float4 r0 = *reinterpret_cast<const float4*>(&rks[(TI-1) + jx - ii][dq]);
                float4 r1 = *reinterpret_cast<const float4*>(&rks[(TI-1) + jx+16 - ii][dq]);
                float a0 = acc[r][0], a1 = acc[r][1];
                a0 = fmaf(q.x, k0.x, a0); a0 = fmaf(q.y, k0.y, a0);
                a0 = fmaf(q.z, k0.z, a0); a0 = fmaf(q.w, k0.w, a0);
                a0 = fmaf(q.x, r0.x, a0); a0 = fmaf(q.y, r0.y, a0);
                a0 = fmaf(q.z, r0.z, a0); a0 = fmaf(q.w, r0.w, a0);
                a1 = fmaf(q.x, k1.x, a1); a1 = fmaf(q.y, k1.y, a1);
                a1 = fmaf(q.z, k1.z, a1); a1 = fmaf(q.w, k1.w, a1);
                a1 = fmaf(q.x, r1.x, a1); a1 = fmaf(q.y, r1.y, a1);
                a1 = fmaf(q.z, r1.z, a1); a1 = fmaf(q.w, r1.w, a1);
                acc[r][0] = a0; acc[r][1] = a1;
            }
        }
#pragma unroll
        for (int r = 0; r < 3; r++) {
            int ii = iy*3 + r;
#pragma unroll
            for (int c = 0; c < 2; c++) {
                int jj = jx + c*16;
                float s = (acc[r][c] + c1s[jj] + c2s[(TI-1) + jj - ii]) * 0.125f;
                if (j0 + jj >= S_LEN) s = -1e30f;
                Ps[ii][jj] = s;
            }
        }
        __syncthreads();

        // online softmax over this tile (one thread per i row)
        if (tid < TI) {
            float mo = mbuf[tid];
            float tm = mo;
#pragma unroll 8
            for (int j = 0; j < TJ; j++) tm = fmaxf(tm, Ps[tid][j]);
            float f = __expf(mo - tm);
            float ssum = 0.f;
#pragma unroll 8
            for (int j = 0; j < TJ; j++) {
                float e = __expf(Ps[tid][j] - tm);
                Ps[tid][j] = e;
                ssum += e;
            }
            lbuf[tid] = lbuf[tid]*f + ssum;
            mbuf[tid] = tm;
            fbuf[tid] = f;
        }
        __syncthreads();

        // PV: thread -> (3 i's) x (4 d's at px*4)
#pragma unroll
        for (int r = 0; r < 3; r++) {
            float fr = fbuf[py*3 + r];
            o[r][0] *= fr; o[r][1] *= fr; o[r][2] *= fr; o[r][3] *= fr;
        }
#pragma unroll 2
        for (int jq = 0; jq < TJ; jq += 4) {
            float4 v0 = *reinterpret_cast<const float4*>(&Vs[jq+0][px*4]);
            float4 v1 = *reinterpret_cast<const float4*>(&Vs[jq+1][px*4]);
            float4 v2 = *reinterpret_cast<const float4*>(&Vs[jq+2][px*4]);
            float4 v3 = *reinterpret_cast<const float4*>(&Vs[jq+3][px*4]);
#pragma unroll
            for (int r = 0; r < 3; r++) {
                float4 p = *reinterpret_cast<const float4*>(&Ps[py*3 + r][jq]);
                o[r][0] = fmaf(p.x, v0.x, o[r][0]); o[r][1] = fmaf(p.x, v0.y, o[r][1]);
                o[r][2] = fmaf(p.x, v0.z, o[r][2]); o[r][3] = fmaf(p.x, v0.w, o[r][3]);
                o[r][0] = fmaf(p.y, v1.x, o[r][0]); o[r][1] = fmaf(p.y, v1.y, o[r][1]);
                o[r][2] = fmaf(p.y, v1.z, o[r][2]); o[r][3] = fmaf(p.y, v1.w, o[r][3]);
                o[r][0] = fmaf(p.z, v2.x, o[r][0]); o[r][1] = fmaf(p.z, v2.y, o[r][1]);
                o[r][2] = fmaf(p.z, v2.z, o[r][2]); o[r][3] = fmaf(p.z, v2.w, o[r][3]);
                o[r][0] = fmaf(p.w, v3.x, o[r][0]); o[r][1] = fmaf(p.w, v3.y, o[r][1]);
                o[r][2] = fmaf(p.w, v3.z, o[r][2]); o[r][3] = fmaf(p.w, v3.w, o[r][3]);
            }
        }
    }
    __syncthreads();

    // epilogue: normalize and write
#pragma unroll
    for (int r = 0; r < 3; r++) {
        int gi = i0 + py*3 + r;
        if (gi < S_LEN) {
            float inv = 1.0f / lbuf[py*3 + r];
            float4 w = make_float4(o[r][0]*inv, o[r][1]*inv, o[r][2]*inv, o[r][3]*inv);
            *reinterpret_cast<float4*>(
                &av[(size_t)(gi*BATCH_N + b)*DMODEL + n*DHEAD + px*4]) = w;
        }
    }
}

// ---------------- final classifier ----------------
__global__ __launch_bounds__(64) void final_kernel(
    const float* __restrict__ core, const float* __restrict__ fcw,
    const float* __restrict__ fcb, float* __restrict__ out)
{
    int idx = blockIdx.x;       // 0..39
    int b = idx / 10, c = idx % 10;
    int lane = threadIdx.x;
    const float* row = &core[(size_t)((S_LEN-1)*BATCH_N + b)*DMODEL];
    float acc = 0.f;
    for (int d = lane; d < DMODEL; d += 64)
        acc = fmaf(row[d], fcw[d*10 + c], acc);
#pragma unroll
    for (int off = 32; off; off >>= 1) acc += __shfl_xor(acc, off);
    if (lane == 0) out[b*10 + c] = acc + fcb[c];
}

extern "C" void kernel_launch(void* const* d_in, const int* in_sizes, int n_in,
                              void* d_out, int out_size, void* d_ws, size_t ws_size,
                              hipStream_t stream)
{
    const float* sig   = (const float*)d_in[0];
    const float* cw    = (const float*)d_in[1];
    const float* cb    = (const float*)d_in[2];
    const float* qkv_w = (const float*)d_in[3];
    const float* r_w   = (const float*)d_in[4];
    const float* o_w   = (const float*)d_in[5];
    const float* ff1_w = (const float*)d_in[6];
    const float* ff1_b = (const float*)d_in[7];
    const float* ff2_w = (const float*)d_in[8];
    const float* ff2_b = (const float*)d_in[9];
    const float* rwb   = (const float*)d_in[10];
    const float* rrb   = (const float*)d_in[11];
    const float* fcw   = (const float*)d_in[12];
    const float* fcb   = (const float*)d_in[13];
    float* out = (float*)d_out;

    float* ws   = (float*)d_ws;
    float* core = ws;                          // 4092*512
    float* pe   = core + (size_t)MROWS*DMODEL; // 2045*512
    float* rk   = pe   + (size_t)RLEN*DMODEL;  // 2045*512
    float* av   = rk   + (size_t)RLEN*DMODEL;  // 4092*512
    float* big  = av   + (size_t)MROWS*DMODEL; // 4092*2048
    float* c1   = big  + (size_t)MROWS*DINNER; // 32*1023
    float* c2   = c1   + (size_t)32*S_LEN;     // 8*2045

    conv_pool_kernel<<<dim3(S_LEN, BATCH_N), 512, 0, stream>>>(sig, cw, cb, core);
    posemb_kernel<<<RLEN, 512, 0, stream>>>(pe);

    for (int l = 0; l < NLAYER; l++) {
        const float* qkvw_l = qkv_w + (size_t)l*DMODEL*(3*DMODEL);
        const float* rw_l   = r_w   + (size_t)l*DMODEL*DMODEL;
        const float* ow_l   = o_w   + (size_t)l*DMODEL*DMODEL;
        const float* f1w_l  = ff1_w + (size_t)l*DMODEL*DINNER;
        const float* f1b_l  = ff1_b + (size_t)l*DINNER;
        const float* f2w_l  = ff2_w + (size_t)l*DINNER*DMODEL;
        const float* f2b_l  = ff2_b + (size_t)l*DMODEL;

        gemm_f32<false,false,false><<<dim3((3*DMODEL)/64, (MROWS+63)/64), 256, 0, stream>>>(
            core, qkvw_l, nullptr, big, MROWS, 3*DMODEL, DMODEL);
        gemm_f32<false,false,false><<<dim3(DMODEL/64, (RLEN+63)/64), 256, 0, stream>>>(
            pe, rw_l, nullptr, rk, RLEN, DMODEL, DMODEL);

        c1_kernel<<<dim3((S_LEN+3)/4, 32), 256, 0, stream>>>(big, rwb, c1);
        c2_kernel<<<dim3((RLEN+3)/4, 8), 256, 0, stream>>>(rk, rrb, c2);

        attn_flash_kernel<<<dim3((S_LEN + TI - 1)/TI, 32), 256, 0, stream>>>(
            big, rk, c1, c2, av);

        gemm_f32<false,false,true><<<dim3(DMODEL/64, (MROWS+63)/64), 256, 0, stream>>>(
            av, ow_l, nullptr, core, MROWS, DMODEL, DMODEL);
        gemm_f32<true,true,false><<<dim3(DINNER/64, (MROWS+63)/64), 256, 0, stream>>>(
            core, f1w_l, f1b_l, big, MROWS, DINNER, DMODEL);
        gemm_f32<true,false,true><<<dim3(DMODEL/64, (MROWS+63)/64), 256, 0, stream>>>(
            big, f2w_l, f2b_l, core, MROWS, DMODEL, DINNER);
    }

    final_kernel<<<40, 64, 0, stream>>>(core, fcw, fcb, out);
}

// Round 3
// 1183.387 us; speedup vs baseline: 11.9282x; 3.2877x over previous
//
#include <hip/hip_runtime.h>
#include <math.h>

#define S_LEN   1023
#define BATCH_N 4
#define DMODEL  512
#define NHEAD   8
#define DHEAD   64
#define DINNER  2048
#define NLAYER  4
#define RAWLEN  8192
#define POOLW   8
#define KERNW   9
#define RLEN    (2*S_LEN-1)   /* 2045 */
#define MROWS   (S_LEN*BATCH_N) /* 4092 */

using bf16x8 = __attribute__((ext_vector_type(8))) short;
using f32x4  = __attribute__((ext_vector_type(4))) float;

__device__ __forceinline__ unsigned short f2bf(float f) {
    union { float f; unsigned int u; } v; v.f = f;
    unsigned int u = v.u;
    return (unsigned short)((u + 0x7fffu + ((u >> 16) & 1u)) >> 16);
}
__device__ __forceinline__ float bf2f(unsigned short h) {
    union { unsigned int u; float f; } v; v.u = ((unsigned int)h) << 16;
    return v.f;
}

// async 16B global -> LDS (dest = wave-uniform base + lane*16)
__device__ __forceinline__ void gload_lds16(const void* g, void* l) {
    using gvoid = const __attribute__((address_space(1))) void;
    using lvoid = __attribute__((address_space(3))) void;
    gvoid* gp = reinterpret_cast<gvoid*>(reinterpret_cast<unsigned long long>(g));
    lvoid* lp = reinterpret_cast<lvoid*>((unsigned int)reinterpret_cast<unsigned long long>(l));
    __builtin_amdgcn_global_load_lds(gp, lp, 16, 0, 0);
}

// ---------------- conv + relu + pool8 -> core f32 + bf16 ----------------
__global__ __launch_bounds__(512) void conv_pool_kernel(
    const float* __restrict__ sig, const float* __restrict__ cw,
    const float* __restrict__ cb, float* __restrict__ core,
    unsigned short* __restrict__ core_bf)
{
    int s = blockIdx.x, b = blockIdx.y, d = threadIdx.x;
    __shared__ float sseg[POOLW + KERNW - 1];
    if (d < POOLW + KERNW - 1) sseg[d] = sig[b*RAWLEN + s*POOLW + d];
    __syncthreads();
    float w[KERNW];
#pragma unroll
    for (int k = 0; k < KERNW; k++) w[k] = cw[k*DMODEL + d];
    float bias = cb[d];
    float acc = 0.f;
#pragma unroll
    for (int p = 0; p < POOLW; p++) {
        float c = bias;
#pragma unroll
        for (int k = 0; k < KERNW; k++) c = fmaf(sseg[p+k], w[k], c);
        acc += fmaxf(c, 0.f);
    }
    float v = acc * (1.0f/POOLW);
    core[(s*BATCH_N + b)*DMODEL + d] = v;
    core_bf[(s*BATCH_N + b)*DMODEL + d] = f2bf(v);
}

// ---------------- positional embedding -> bf16 ----------------
__global__ __launch_bounds__(512) void posemb_kernel(unsigned short* __restrict__ pe)
{
    int j = blockIdx.x, d = threadIdx.x;
    float pos = (float)(S_LEN - 1 - j);
    int i = (d < 256) ? d : d - 256;
    float invf = powf(10000.0f, -(float)i * (1.0f/256.0f));
    float a = pos * invf;
    pe[j*DMODEL + d] = f2bf((d < 256) ? sinf(a) : cosf(a));
}

// ---------------- weight transpose + cvt: W[K][N] f32 -> Wt[N][K] bf16 ----------------
__global__ __launch_bounds__(256) void transpose_cvt_kernel(
    const float* __restrict__ W, unsigned short* __restrict__ Wt, int K, int N)
{
    __shared__ float L[32][33];
    int n0 = blockIdx.x*32, k0 = blockIdx.y*32;
    int t = threadIdx.x;
    int kk = t>>3, nq = (t&7)*4;
    float4 v = *reinterpret_cast<const float4*>(&W[(size_t)(k0+kk)*N + n0 + nq]);
    L[kk][nq+0]=v.x; L[kk][nq+1]=v.y; L[kk][nq+2]=v.z; L[kk][nq+3]=v.w;
    __syncthreads();
    int nn = t>>3, kq = (t&7)*4;
    ushort4 o;
    o.x = f2bf(L[kq+0][nn]); o.y = f2bf(L[kq+1][nn]);
    o.z = f2bf(L[kq+2][nn]); o.w = f2bf(L[kq+3][nn]);
    *reinterpret_cast<ushort4*>(&Wt[(size_t)(n0+nn)*K + k0 + kq]) = o;
}

// ---------------- MFMA GEMM: A(MxK bf16) @ Bt(NxK bf16)^T -> C ----------------
// 128x128 tile, BK=32, 4 waves, m97 structure.
template<bool ACCUM, bool BIAS, bool RELU, bool WF32, bool WBF>
__global__ __launch_bounds__(256) void gemm_mfma(
    const unsigned short* __restrict__ A, const unsigned short* __restrict__ Bt,
    const float* __restrict__ bias, float* __restrict__ C,
    unsigned short* __restrict__ Cb, int M, int N, int K)
{
    __shared__ unsigned short As[128*32];
    __shared__ unsigned short Bs[128*32];
    int bm = blockIdx.y * 128, bn = blockIdx.x * 128;
    int tid = threadIdx.x, lane = tid & 63, wid = tid >> 6;
    int wr = wid >> 1, wc = wid & 1;

    f32x4 acc[4][4];
#pragma unroll
    for (int m=0;m<4;m++)
#pragma unroll
        for (int n=0;n<4;n++) acc[m][n] = (f32x4){0.f,0.f,0.f,0.f};

    // staging addresses: wave wid stages chunks {wid, wid+4} of A and B
    int r0 = wid*16 + (lane>>2);
    int r1 = r0 + 64;
    int slot = (lane&3)*8;
    int ga0 = bm + r0; if (ga0 > M-1) ga0 = M-1;
    int ga1 = bm + r1; if (ga1 > M-1) ga1 = M-1;
    const unsigned short* pA0 = A  + (size_t)ga0*K + slot;
    const unsigned short* pA1 = A  + (size_t)ga1*K + slot;
    const unsigned short* pB0 = Bt + (size_t)(bn + r0)*K + slot;
    const unsigned short* pB1 = Bt + (size_t)(bn + r1)*K + slot;
    char* lA0 = (char*)As + wid*1024;
    char* lA1 = (char*)As + (wid+4)*1024;
    char* lB0 = (char*)Bs + wid*1024;
    char* lB1 = (char*)Bs + (wid+4)*1024;

    int ar = wr*64 + (lane&15);
    int br = wc*64 + (lane&15);
    int kc = (lane>>4)*8;

    for (int k0 = 0; k0 < K; k0 += 32) {
        __syncthreads();
        gload_lds16(pA0, lA0);
        gload_lds16(pA1, lA1);
        gload_lds16(pB0, lB0);
        gload_lds16(pB1, lB1);
        pA0 += 32; pA1 += 32; pB0 += 32; pB1 += 32;
        __syncthreads();
        bf16x8 a[4], b[4];
#pragma unroll
        for (int m=0;m<4;m++) a[m] = *reinterpret_cast<const bf16x8*>(&As[(ar + m*16)*32 + kc]);
#pragma unroll
        for (int n=0;n<4;n++) b[n] = *reinterpret_cast<const bf16x8*>(&Bs[(br + n*16)*32 + kc]);
#pragma unroll
        for (int m=0;m<4;m++)
#pragma unroll
            for (int n=0;n<4;n++)
                acc[m][n] = __builtin_amdgcn_mfma_f32_16x16x32_bf16(a[m], b[n], acc[m][n], 0,0,0);
    }

    int col0 = bn + wc*64 + (lane&15);
    int rbase = bm + wr*64 + (lane>>4)*4;
#pragma unroll
    for (int m=0;m<4;m++) {
#pragma unroll
        for (int n=0;n<4;n++) {
            int col = col0 + n*16;
            float bv = BIAS ? bias[col] : 0.f;
#pragma unroll
            for (int r=0;r<4;r++) {
                int row = rbase + m*16 + r;
                if (row < M) {
                    float v = acc[m][n][r] + bv;
                    if (RELU) v = fmaxf(v, 0.f);
                    size_t off = (size_t)row*N + col;
                    if (ACCUM) v += C[off];
                    if (WF32) C[off] = v;
                    if (WBF)  Cb[off] = f2bf(v);
                }
            }
        }
    }
}

// ---------------- MFMA flash attention ----------------
// block = (i-tile of 32, bn). Qw=q+rwb, Qr=q+rrb staged bf16.
// per j-tile: AC = Qw@K^T (32x32), BD = Qr@rkwin^T (32x64), softmax, PV accum.
#define TI 32
#define TJ 32
#define WROWS 64
#define QSTR 72   /* bf16 row stride for Qw/Qr/Ks/rks */
#define VSTR 40   /* bf16 row stride Vt */
#define PSTR 40   /* bf16 row stride Pb */
#define ACSTR 36  /* f32 row stride Sac */
#define BDSTR 68  /* f32 row stride Sbd */

__global__ __launch_bounds__(256) void attn_mfma_kernel(
    const unsigned short* __restrict__ heads, // (S,B,1536) bf16
    const unsigned short* __restrict__ rk,    // (2045,512) bf16
    const float* __restrict__ rwb, const float* __restrict__ rrb,
    unsigned short* __restrict__ av)          // (S,B,512) bf16
{
    int i0 = blockIdx.x * TI;
    int bn = blockIdx.y; int b = bn >> 3, n = bn & 7;
    int tid = threadIdx.x, lane = tid & 63, wid = tid >> 6;

    __shared__ unsigned short Qw[TI*QSTR], Qr[TI*QSTR];
    __shared__ unsigned short Ks[TJ*QSTR];
    __shared__ unsigned short rks[WROWS*QSTR];
    __shared__ unsigned short Vt[DHEAD*VSTR];
    __shared__ unsigned short Pb[TI*PSTR];
    __shared__ float Sac[TI*ACSTR];
    __shared__ float Sbd[TI*BDSTR];
    __shared__ float mrow[TI], lrow[TI], frow[TI];

    // stage Q with biases folded
    {
        int r = tid>>3, sl = (tid&7)*8;
        int gi = i0 + r; if (gi > S_LEN-1) gi = S_LEN-1;
        const unsigned short* src = heads + (size_t)(gi*BATCH_N + b)*1536 + n*64 + sl;
        ushort4 u0 = *reinterpret_cast<const ushort4*>(src);
        ushort4 u1 = *reinterpret_cast<const ushort4*>(src+4);
        float q[8] = {bf2f(u0.x),bf2f(u0.y),bf2f(u0.z),bf2f(u0.w),
                      bf2f(u1.x),bf2f(u1.y),bf2f(u1.z),bf2f(u1.w)};
#pragma unroll
        for (int e=0;e<8;e++) {
            Qw[r*QSTR + sl + e] = f2bf(q[e] + rwb[n*64 + sl + e]);
            Qr[r*QSTR + sl + e] = f2bf(q[e] + rrb[n*64 + sl + e]);
        }
    }
    if (tid < TI) { mrow[tid] = -1e30f; lrow[tid] = 0.f; }
    __syncthreads();

    int mi = wid >> 1;          // i-block (0/1)
    int ni0 = (wid & 1) * 2;    // d/window blocks {ni0, ni0+1}
    int kc = (lane>>4)*8;
    int arow = mi*16 + (lane&15);

    // hoist Q fragments (invariant across tiles)
    bf16x8 qwf0 = *reinterpret_cast<const bf16x8*>(&Qw[arow*QSTR + kc]);
    bf16x8 qwf1 = *reinterpret_cast<const bf16x8*>(&Qw[arow*QSTR + 32 + kc]);
    bf16x8 qrf0 = *reinterpret_cast<const bf16x8*>(&Qr[arow*QSTR + kc]);
    bf16x8 qrf1 = *reinterpret_cast<const bf16x8*>(&Qr[arow*QSTR + 32 + kc]);

    f32x4 Oa[2];
    Oa[0] = (f32x4){0.f,0.f,0.f,0.f};
    Oa[1] = (f32x4){0.f,0.f,0.f,0.f};

    for (int t = 0; t < 32; t++) {
        int j0 = t * TJ;
        int base_r = (S_LEN-1) - i0 - (TI-1) + j0;
        __syncthreads();   // protect K/V/rk from prev tile's PV readers
        // stage K
        {
            int r = tid>>3, sl = (tid&7)*8;
            int gj = j0 + r; if (gj > S_LEN-1) gj = S_LEN-1;
            const unsigned short* src = heads + (size_t)(gj*BATCH_N + b)*1536 + 512 + n*64 + sl;
            *reinterpret_cast<ushort4*>(&Ks[r*QSTR + sl])   = *reinterpret_cast<const ushort4*>(src);
            *reinterpret_cast<ushort4*>(&Ks[r*QSTR + sl+4]) = *reinterpret_cast<const ushort4*>(src+4);
        }
        // stage V transposed: Vt[d][j]
        {
            int j = tid>>3, db = (tid&7)*8;
            int gj = j0 + j; if (gj > S_LEN-1) gj = S_LEN-1;
            const unsigned short* src = heads + (size_t)(gj*BATCH_N + b)*1536 + 1024 + n*64 + db;
            ushort4 u0 = *reinterpret_cast<const ushort4*>(src);
            ushort4 u1 = *reinterpret_cast<const ushort4*>(src+4);
            Vt[(db+0)*VSTR + j] = u0.x; Vt[(db+1)*VSTR + j] = u0.y;
            Vt[(db+2)*VSTR + j] = u0.z; Vt[(db+3)*VSTR + j] = u0.w;
            Vt[(db+4)*VSTR + j] = u1.x; Vt[(db+5)*VSTR + j] = u1.y;
            Vt[(db+6)*VSTR + j] = u1.z; Vt[(db+7)*VSTR + j] = u1.w;
        }
        // stage rk window (64 rows)
#pragma unroll
        for (int q=0;q<2;q++) {
            int unit = tid + q*256;
            int r = unit>>3, sl = (unit&7)*8;
            int gr = base_r + r; gr = gr < 0 ? 0 : (gr > RLEN-1 ? RLEN-1 : gr);
            const unsigned short* src = rk + (size_t)gr*DMODEL + n*64 + sl;
            *reinterpret_cast<ushort4*>(&rks[r*QSTR + sl])   = *reinterpret_cast<const ushort4*>(src);
            *reinterpret_cast<ushort4*>(&rks[r*QSTR + sl+4]) = *reinterpret_cast<const ushort4*>(src+4);
        }
        __syncthreads();

        // scores
        {
            int ci = (wid&1)*16 + (lane&15);
            bf16x8 kf0 = *reinterpret_cast<const bf16x8*>(&Ks[ci*QSTR + kc]);
            bf16x8 kf1 = *reinterpret_cast<const bf16x8*>(&Ks[ci*QSTR + 32 + kc]);
            f32x4 s = (f32x4){0.f,0.f,0.f,0.f};
            s = __builtin_amdgcn_mfma_f32_16x16x32_bf16(qwf0, kf0, s, 0,0,0);
            s = __builtin_amdgcn_mfma_f32_16x16x32_bf16(qwf1, kf1, s, 0,0,0);
            int rw = mi*16 + (lane>>4)*4;
#pragma unroll
            for (int r=0;r<4;r++) Sac[(rw+r)*ACSTR + ci] = s[r];
#pragma unroll
            for (int nn=0;nn<2;nn++) {
                int w = (ni0+nn)*16 + (lane&15);
                bf16x8 rf0 = *reinterpret_cast<const bf16x8*>(&rks[w*QSTR + kc]);
                bf16x8 rf1 = *reinterpret_cast<const bf16x8*>(&rks[w*QSTR + 32 + kc]);
                f32x4 sb = (f32x4){0.f,0.f,0.f,0.f};
                sb = __builtin_amdgcn_mfma_f32_16x16x32_bf16(qrf0, rf0, sb, 0,0,0);
                sb = __builtin_amdgcn_mfma_f32_16x16x32_bf16(qrf1, rf1, sb, 0,0,0);
#pragma unroll
                for (int r=0;r<4;r++) Sbd[(rw+r)*BDSTR + w] = sb[r];
            }
        }
        __syncthreads();

        // online softmax: one thread per row
        if (tid < TI) {
            int il = tid;
            int shift = (TI-1) - il;
            float mo = mrow[il];
            float tm = mo;
            float sc[TJ];
#pragma unroll
            for (int j=0;j<TJ;j++) {
                float v = (Sac[il*ACSTR + j] + Sbd[il*BDSTR + shift + j]) * 0.125f;
                if (j0 + j >= S_LEN) v = -1e30f;
                sc[j] = v;
                tm = fmaxf(tm, v);
            }
            float f = __expf(mo - tm);
            float ssum = 0.f;
#pragma unroll
            for (int j=0;j<TJ;j++) {
                unsigned short eb = f2bf(__expf(sc[j] - tm));
                Pb[il*PSTR + j] = eb;
                ssum += bf2f(eb);
            }
            mrow[il] = tm;
            lrow[il] = lrow[il]*f + ssum;
            frow[il] = f;
        }
        __syncthreads();

        // PV: rescale O then accumulate P @ V^T
        {
            int rw = mi*16 + (lane>>4)*4;
            float f0 = frow[rw+0], f1 = frow[rw+1], f2 = frow[rw+2], f3 = frow[rw+3];
#pragma unroll
            for (int nn=0;nn<2;nn++) {
                Oa[nn][0] *= f0; Oa[nn][1] *= f1; Oa[nn][2] *= f2; Oa[nn][3] *= f3;
            }
            int prow = mi*16 + (lane&15);
            bf16x8 pf = *reinterpret_cast<const bf16x8*>(&Pb[prow*PSTR + kc]);
#pragma unroll
            for (int nn=0;nn<2;nn++) {
                int vr = (ni0+nn)*16 + (lane&15);
                bf16x8 vf = *reinterpret_cast<const bf16x8*>(&Vt[vr*VSTR + kc]);
                Oa[nn] = __builtin_amdgcn_mfma_f32_16x16x32_bf16(pf, vf, Oa[nn], 0,0,0);
            }
        }
    }
    __syncthreads();

    // epilogue
    {
        int rw = mi*16 + (lane>>4)*4;
        float linv[4];
#pragma unroll
        for (int r=0;r<4;r++) linv[r] = 1.0f / lrow[rw+r];
#pragma unroll
        for (int nn=0;nn<2;nn++) {
            int d = (ni0+nn)*16 + (lane&15);
#pragma unroll
            for (int r=0;r<4;r++) {
                int gi = i0 + rw + r;
                if (gi < S_LEN)
                    av[(size_t)(gi*BATCH_N + b)*DMODEL + n*64 + d] = f2bf(Oa[nn][r]*linv[r]);
            }
        }
    }
}

// ---------------- final classifier (f32) ----------------
__global__ __launch_bounds__(64) void final_kernel(
    const float* __restrict__ core, const float* __restrict__ fcw,
    const float* __restrict__ fcb, float* __restrict__ out)
{
    int idx = blockIdx.x;
    int b = idx / 10, c = idx % 10;
    int lane = threadIdx.x;
    const float* row = &core[(size_t)((S_LEN-1)*BATCH_N + b)*DMODEL];
    float acc = 0.f;
    for (int d = lane; d < DMODEL; d += 64)
        acc = fmaf(row[d], fcw[d*10 + c], acc);
#pragma unroll
    for (int off = 32; off; off >>= 1) acc += __shfl_xor(acc, off);
    if (lane == 0) out[b*10 + c] = acc + fcb[c];
}

extern "C" void kernel_launch(void* const* d_in, const int* in_sizes, int n_in,
                              void* d_out, int out_size, void* d_ws, size_t ws_size,
                              hipStream_t stream)
{
    const float* sig   = (const float*)d_in[0];
    const float* cw    = (const float*)d_in[1];
    const float* cb    = (const float*)d_in[2];
    const float* qkv_w = (const float*)d_in[3];
    const float* r_w   = (const float*)d_in[4];
    const float* o_w   = (const float*)d_in[5];
    const float* ff1_w = (const float*)d_in[6];
    const float* ff1_b = (const float*)d_in[7];
    const float* ff2_w = (const float*)d_in[8];
    const float* ff2_b = (const float*)d_in[9];
    const float* rwb   = (const float*)d_in[10];
    const float* rrb   = (const float*)d_in[11];
    const float* fcw   = (const float*)d_in[12];
    const float* fcb   = (const float*)d_in[13];
    float* out = (float*)d_out;

    // workspace layout
    float* core = (float*)d_ws;                                    // 4092*512 f32
    unsigned short* core_bf = (unsigned short*)(core + (size_t)MROWS*DMODEL);
    unsigned short* pe_bf   = core_bf + (size_t)MROWS*DMODEL;      // 2045*512
    unsigned short* rk_bf   = pe_bf   + (size_t)RLEN*DMODEL;       // 2045*512
    unsigned short* av_bf   = rk_bf   + (size_t)RLEN*DMODEL;       // 4092*512
    unsigned short* big_bf  = av_bf   + (size_t)MROWS*DMODEL;      // 4092*2048 (heads | ffn hidden)
    unsigned short* qkvT = big_bf + (size_t)MROWS*DINNER;          // 1536*512
    unsigned short* rwT  = qkvT + (size_t)(3*DMODEL)*DMODEL;       // 512*512
    unsigned short* owT  = rwT  + (size_t)DMODEL*DMODEL;           // 512*512
    unsigned short* ff1T = owT  + (size_t)DMODEL*DMODEL;           // 2048*512
    unsigned short* ff2T = ff1T + (size_t)DINNER*DMODEL;           // 512*2048

    conv_pool_kernel<<<dim3(S_LEN, BATCH_N), 512, 0, stream>>>(sig, cw, cb, core, core_bf);
    posemb_kernel<<<RLEN, 512, 0, stream>>>(pe_bf);

    for (int l = 0; l < NLAYER; l++) {
        // per-layer weight transposes (f32 -> bf16, K x N -> N x K)
        transpose_cvt_kernel<<<dim3(48,16), 256, 0, stream>>>(
            qkv_w + (size_t)l*DMODEL*(3*DMODEL), qkvT, DMODEL, 3*DMODEL);
        transpose_cvt_kernel<<<dim3(16,16), 256, 0, stream>>>(
            r_w + (size_t)l*DMODEL*DMODEL, rwT, DMODEL, DMODEL);
        transpose_cvt_kernel<<<dim3(16,16), 256, 0, stream>>>(
            o_w + (size_t)l*DMODEL*DMODEL, owT, DMODEL, DMODEL);
        transpose_cvt_kernel<<<dim3(64,16), 256, 0, stream>>>(
            ff1_w + (size_t)l*DMODEL*DINNER, ff1T, DMODEL, DINNER);
        transpose_cvt_kernel<<<dim3(16,64), 256, 0, stream>>>(
            ff2_w + (size_t)l*DINNER*DMODEL, ff2T, DINNER, DMODEL);

        // heads = core @ qkv_w  -> bf16
        gemm_mfma<false,false,false,false,true><<<dim3(12,32), 256, 0, stream>>>(
            core_bf, qkvT, nullptr, nullptr, big_bf, MROWS, 3*DMODEL, DMODEL);
        // rk = pe @ r_w -> bf16
        gemm_mfma<false,false,false,false,true><<<dim3(4,16), 256, 0, stream>>>(
            pe_bf, rwT, nullptr, nullptr, rk_bf, RLEN, DMODEL, DMODEL);
        // attention
        attn_mfma_kernel<<<dim3(32,32), 256, 0, stream>>>(big_bf, rk_bf, rwb, rrb, av_bf);
        // core += av @ o_w  (f32 + bf16 mirror)
        gemm_mfma<true,false,false,true,true><<<dim3(4,32), 256, 0, stream>>>(
            av_bf, owT, nullptr, core, core_bf, MROWS, DMODEL, DMODEL);
        // hid = relu(core @ ff1 + b) -> bf16 (overwrites heads region)
        gemm_mfma<false,true,true,false,true><<<dim3(16,32), 256, 0, stream>>>(
            core_bf, ff1T, ff1_b + (size_t)l*DINNER, nullptr, big_bf, MROWS, DINNER, DMODEL);
        // core += hid @ ff2 + b  (f32 + bf16 mirror)
        gemm_mfma<true,true,false,true,true><<<dim3(4,32), 256, 0, stream>>>(
            big_bf, ff2T, ff2_b + (size_t)l*DMODEL, core, core_bf, MROWS, DMODEL, DINNER);
    }

    final_kernel<<<40, 64, 0, stream>>>(core, fcw, fcb, out);
}

// Round 5
// 843.167 us; speedup vs baseline: 16.7413x; 1.4035x over previous
//
#include <hip/hip_runtime.h>
#include <math.h>

#define S_LEN   1023
#define BATCH_N 4
#define DMODEL  512
#define NHEAD   8
#define DHEAD   64
#define DINNER  2048
#define NLAYER  4
#define RAWLEN  8192
#define POOLW   8
#define KERNW   9
#define RLEN    (2*S_LEN-1)   /* 2045 */
#define MROWS   (S_LEN*BATCH_N) /* 4092 */

using bf16x8 = __attribute__((ext_vector_type(8))) short;
using f32x4  = __attribute__((ext_vector_type(4))) float;

__device__ __forceinline__ unsigned short f2bf(float f) {
    union { float f; unsigned int u; } v; v.f = f;
    unsigned int u = v.u;
    return (unsigned short)((u + 0x7fffu + ((u >> 16) & 1u)) >> 16);
}
__device__ __forceinline__ float bf2f(unsigned short h) {
    union { unsigned int u; float f; } v; v.u = ((unsigned int)h) << 16;
    return v.f;
}

// async 16B global -> LDS (dest = wave-uniform base + lane*16)
__device__ __forceinline__ void gload_lds16(const void* g, void* l) {
    using gvoid = const __attribute__((address_space(1))) void;
    using lvoid = __attribute__((address_space(3))) void;
    gvoid* gp = reinterpret_cast<gvoid*>(reinterpret_cast<unsigned long long>(g));
    lvoid* lp = reinterpret_cast<lvoid*>((unsigned int)reinterpret_cast<unsigned long long>(l));
    __builtin_amdgcn_global_load_lds(gp, lp, 16, 0, 0);
}

// ---------------- conv + relu + pool8 -> core f32 + bf16 ----------------
__global__ __launch_bounds__(512) void conv_pool_kernel(
    const float* __restrict__ sig, const float* __restrict__ cw,
    const float* __restrict__ cb, float* __restrict__ core,
    unsigned short* __restrict__ core_bf)
{
    int s = blockIdx.x, b = blockIdx.y, d = threadIdx.x;
    __shared__ float sseg[POOLW + KERNW - 1];
    if (d < POOLW + KERNW - 1) sseg[d] = sig[b*RAWLEN + s*POOLW + d];
    __syncthreads();
    float w[KERNW];
#pragma unroll
    for (int k = 0; k < KERNW; k++) w[k] = cw[k*DMODEL + d];
    float bias = cb[d];
    float acc = 0.f;
#pragma unroll
    for (int p = 0; p < POOLW; p++) {
        float c = bias;
#pragma unroll
        for (int k = 0; k < KERNW; k++) c = fmaf(sseg[p+k], w[k], c);
        acc += fmaxf(c, 0.f);
    }
    float v = acc * (1.0f/POOLW);
    core[(s*BATCH_N + b)*DMODEL + d] = v;
    core_bf[(s*BATCH_N + b)*DMODEL + d] = f2bf(v);
}

// ---------------- positional embedding -> bf16 ----------------
__global__ __launch_bounds__(512) void posemb_kernel(unsigned short* __restrict__ pe)
{
    int j = blockIdx.x, d = threadIdx.x;
    float pos = (float)(S_LEN - 1 - j);
    int i = (d < 256) ? d : d - 256;
    float invf = powf(10000.0f, -(float)i * (1.0f/256.0f));
    float a = pos * invf;
    pe[j*DMODEL + d] = f2bf((d < 256) ? sinf(a) : cosf(a));
}

// ---------------- weight transpose + cvt: W[K][N] f32 -> Wt[N][K] bf16 ----------------
__global__ __launch_bounds__(256) void transpose_cvt_kernel(
    const float* __restrict__ W, unsigned short* __restrict__ Wt, int K, int N)
{
    __shared__ float L[32][33];
    int n0 = blockIdx.x*32, k0 = blockIdx.y*32;
    int t = threadIdx.x;
    int kk = t>>3, nq = (t&7)*4;
    float4 v = *reinterpret_cast<const float4*>(&W[(size_t)(k0+kk)*N + n0 + nq]);
    L[kk][nq+0]=v.x; L[kk][nq+1]=v.y; L[kk][nq+2]=v.z; L[kk][nq+3]=v.w;
    __syncthreads();
    int nn = t>>3, kq = (t&7)*4;
    ushort4 o;
    o.x = f2bf(L[kq+0][nn]); o.y = f2bf(L[kq+1][nn]);
    o.z = f2bf(L[kq+2][nn]); o.w = f2bf(L[kq+3][nn]);
    *reinterpret_cast<ushort4*>(&Wt[(size_t)(n0+nn)*K + k0 + kq]) = o;
}

// ---------------- MFMA GEMM: A(MxK bf16) @ Bt(NxK bf16)^T -> C ----------------
// BM=128, BN in {64,128}, BK=32, 4 waves.
template<int BN, bool ACCUM, bool BIAS, bool RELU, bool WF32, bool WBF>
__global__ __launch_bounds__(256) void gemm_mfma(
    const unsigned short* __restrict__ A, const unsigned short* __restrict__ Bt,
    const float* __restrict__ bias, float* __restrict__ C,
    unsigned short* __restrict__ Cb, int M, int N, int K)
{
    constexpr int MF = (BN == 128) ? 4 : 2;
    __shared__ unsigned short As[128*32];
    __shared__ unsigned short Bs[BN*32];
    int bm = blockIdx.y * 128, bn = blockIdx.x * BN;
    int tid = threadIdx.x, lane = tid & 63, wid = tid >> 6;

    f32x4 acc[MF][4];
#pragma unroll
    for (int m=0;m<MF;m++)
#pragma unroll
        for (int n=0;n<4;n++) acc[m][n] = (f32x4){0.f,0.f,0.f,0.f};

    int r0 = wid*16 + (lane>>2);
    int slot = (lane&3)*8;
    int ga0 = bm + r0;      if (ga0 > M-1) ga0 = M-1;
    int ga1 = bm + r0 + 64; if (ga1 > M-1) ga1 = M-1;
    const unsigned short* pA0 = A  + (size_t)ga0*K + slot;
    const unsigned short* pA1 = A  + (size_t)ga1*K + slot;
    const unsigned short* pB0 = Bt + (size_t)(bn + r0)*K + slot;
    const unsigned short* pB1 = (BN==128) ? Bt + (size_t)(bn + r0 + 64)*K + slot : nullptr;
    char* lA0 = (char*)As + wid*1024;
    char* lA1 = (char*)As + (wid+4)*1024;
    char* lB0 = (char*)Bs + wid*1024;
    char* lB1 = (char*)Bs + (wid+4)*1024;

    int ar = (BN==128 ? (wid>>1)*64 : wid*32) + (lane&15);
    int br = (BN==128 ? (wid&1)*64 : 0) + (lane&15);
    int kc = (lane>>4)*8;

    for (int k0 = 0; k0 < K; k0 += 32) {
        __syncthreads();
        gload_lds16(pA0, lA0);
        gload_lds16(pA1, lA1);
        gload_lds16(pB0, lB0);
        if (BN == 128) gload_lds16(pB1, lB1);
        pA0 += 32; pA1 += 32; pB0 += 32; if (BN==128) pB1 += 32;
        __syncthreads();
        bf16x8 a[MF], b[4];
#pragma unroll
        for (int m=0;m<MF;m++) a[m] = *reinterpret_cast<const bf16x8*>(&As[(ar + m*16)*32 + kc]);
#pragma unroll
        for (int n=0;n<4;n++) b[n] = *reinterpret_cast<const bf16x8*>(&Bs[(br + n*16)*32 + kc]);
#pragma unroll
        for (int m=0;m<MF;m++)
#pragma unroll
            for (int n=0;n<4;n++)
                acc[m][n] = __builtin_amdgcn_mfma_f32_16x16x32_bf16(a[m], b[n], acc[m][n], 0,0,0);
    }

    int col0 = bn + (BN==128 ? (wid&1)*64 : 0) + (lane&15);
    int rbase = bm + (BN==128 ? (wid>>1)*64 : wid*32) + (lane>>4)*4;
#pragma unroll
    for (int m=0;m<MF;m++) {
#pragma unroll
        for (int n=0;n<4;n++) {
            int col = col0 + n*16;
            float bv = BIAS ? bias[col] : 0.f;
#pragma unroll
            for (int r=0;r<4;r++) {
                int row = rbase + m*16 + r;
                if (row < M) {
                    float v = acc[m][n][r] + bv;
                    if (RELU) v = fmaxf(v, 0.f);
                    size_t off = (size_t)row*N + col;
                    if (ACCUM) v += C[off];
                    if (WF32) C[off] = v;
                    if (WBF)  Cb[off] = f2bf(v);
                }
            }
        }
    }
}

// ---------------- MFMA flash attention, all operands direct-from-global ----------------
#define TI 32
#define TJ 32
#define PSTR 40   /* bf16 row stride Pb */
#define ACSTR 36  /* f32 row stride Sac */
#define BDSTR 68  /* f32 row stride Sbd */

__global__ __launch_bounds__(256) void attn_mfma_kernel(
    const unsigned short* __restrict__ heads, // (S,B,1536) bf16
    const unsigned short* __restrict__ rk,    // (2045,512) bf16
    const float* __restrict__ rwb, const float* __restrict__ rrb,
    unsigned short* __restrict__ av)          // (S,B,512) bf16
{
    int i0 = blockIdx.x * TI;
    int bn = blockIdx.y; int b = bn >> 3, n = bn & 7;
    int tid = threadIdx.x, lane = tid & 63, wid = tid >> 6;
    int mi = wid >> 1;          // i-row block (0/1)
    int half = wid & 1;         // col-half assignment
    int kc = (lane>>4)*8;
    int l15 = lane & 15;

    __shared__ float Sac[TI*ACSTR];
    __shared__ float Sbd[TI*BDSTR];
    __shared__ unsigned short Pb[TI*PSTR];
    __shared__ float mrow[TI], lrow[TI], frow[TI];

    const int base0 = (S_LEN-1) - i0 - (TI-1);   // rk global row at window offset 0

    // ---- Q fragments direct from global, biases folded ----
    bf16x8 qwf0, qwf1, qrf0, qrf1;
    {
        int gi = i0 + mi*16 + l15; if (gi > S_LEN-1) gi = S_LEN-1;
        const unsigned short* qb = heads + (size_t)(gi*BATCH_N + b)*1536 + n*64;
        bf16x8 u0 = *reinterpret_cast<const bf16x8*>(qb + kc);
        bf16x8 u1 = *reinterpret_cast<const bf16x8*>(qb + 32 + kc);
#pragma unroll
        for (int e=0;e<8;e++) {
            float f0 = bf2f((unsigned short)u0[e]);
            float f1 = bf2f((unsigned short)u1[e]);
            qwf0[e] = (short)f2bf(f0 + rwb[n*64 + kc + e]);
            qrf0[e] = (short)f2bf(f0 + rrb[n*64 + kc + e]);
            qwf1[e] = (short)f2bf(f1 + rwb[n*64 + 32 + kc + e]);
            qrf1[e] = (short)f2bf(f1 + rrb[n*64 + 32 + kc + e]);
        }
    }
    if (tid < TI) { mrow[tid] = -1e30f; lrow[tid] = 0.f; }

    f32x4 Oa[2];
    Oa[0] = (f32x4){0.f,0.f,0.f,0.f};
    Oa[1] = (f32x4){0.f,0.f,0.f,0.f};

    int rw = mi*16 + (lane>>4)*4;

    for (int t = 0; t < 32; t++) {
        int j0 = t * TJ;
        __syncthreads();   // separates softmax(t-1) Sbd reads / PV(t-1) Pb reads from writes below

        // ---- AC scores: B-frag = K rows direct from global ----
        {
            int gj = j0 + half*16 + l15; if (gj > S_LEN-1) gj = S_LEN-1;
            const unsigned short* kb = heads + (size_t)(gj*BATCH_N + b)*1536 + 512 + n*64;
            bf16x8 kf0 = *reinterpret_cast<const bf16x8*>(kb + kc);
            bf16x8 kf1 = *reinterpret_cast<const bf16x8*>(kb + 32 + kc);
            f32x4 s = (f32x4){0.f,0.f,0.f,0.f};
            s = __builtin_amdgcn_mfma_f32_16x16x32_bf16(qwf0, kf0, s, 0,0,0);
            s = __builtin_amdgcn_mfma_f32_16x16x32_bf16(qwf1, kf1, s, 0,0,0);
            int ci = half*16 + l15;
#pragma unroll
            for (int r=0;r<4;r++) Sac[(rw+r)*ACSTR + ci] = s[r];
        }
        // ---- BD scores into rolling Sbd cache (phys col = off & 63) ----
        if (t == 0) {
#pragma unroll
            for (int nn=0;nn<2;nn++) {
                int w = (half*2+nn)*16 + l15;         // phys col == off at t=0
                int gr = base0 + w; gr = gr < 0 ? 0 : (gr > RLEN-1 ? RLEN-1 : gr);
                const unsigned short* rb = rk + (size_t)gr*DMODEL + n*64;
                bf16x8 rf0 = *reinterpret_cast<const bf16x8*>(rb + kc);
                bf16x8 rf1 = *reinterpret_cast<const bf16x8*>(rb + 32 + kc);
                f32x4 sb = (f32x4){0.f,0.f,0.f,0.f};
                sb = __builtin_amdgcn_mfma_f32_16x16x32_bf16(qrf0, rf0, sb, 0,0,0);
                sb = __builtin_amdgcn_mfma_f32_16x16x32_bf16(qrf1, rf1, sb, 0,0,0);
#pragma unroll
                for (int r=0;r<4;r++) Sbd[(rw+r)*BDSTR + w] = sb[r];
            }
        } else {
            int pblk = ((t & 1) ? 0 : 2) + half;      // 2 new 16-col blocks this tile
            int w = pblk*16 + l15;                    // phys col
            int off = 32*(t+1) + (w & 31);            // window offset for this phys col
            int gr = base0 + off; gr = gr < 0 ? 0 : (gr > RLEN-1 ? RLEN-1 : gr);
            const unsigned short* rb = rk + (size_t)gr*DMODEL + n*64;
            bf16x8 rf0 = *reinterpret_cast<const bf16x8*>(rb + kc);
            bf16x8 rf1 = *reinterpret_cast<const bf16x8*>(rb + 32 + kc);
            f32x4 sb = (f32x4){0.f,0.f,0.f,0.f};
            sb = __builtin_amdgcn_mfma_f32_16x16x32_bf16(qrf0, rf0, sb, 0,0,0);
            sb = __builtin_amdgcn_mfma_f32_16x16x32_bf16(qrf1, rf1, sb, 0,0,0);
#pragma unroll
            for (int r=0;r<4;r++) Sbd[(rw+r)*BDSTR + w] = sb[r];
        }
        __syncthreads();

        // ---- parallel online softmax: thread -> (row = tid>>3, 4 j at (tid&7)*4) ----
        {
            int r = tid>>3, seg = tid&7, jl = seg*4;
            float4 ac = *reinterpret_cast<const float4*>(&Sac[r*ACSTR + jl]);
            int cbase = 32*t + (TI-1) - r;    // phys col = (cbase + j) & 63
            float s0 = (ac.x + Sbd[r*BDSTR + ((cbase+jl+0)&63)]) * 0.125f;
            float s1 = (ac.y + Sbd[r*BDSTR + ((cbase+jl+1)&63)]) * 0.125f;
            float s2 = (ac.z + Sbd[r*BDSTR + ((cbase+jl+2)&63)]) * 0.125f;
            float s3 = (ac.w + Sbd[r*BDSTR + ((cbase+jl+3)&63)]) * 0.125f;
            int jg = j0 + jl;
            if (jg+0 >= S_LEN) s0 = -1e30f;
            if (jg+1 >= S_LEN) s1 = -1e30f;
            if (jg+2 >= S_LEN) s2 = -1e30f;
            if (jg+3 >= S_LEN) s3 = -1e30f;
            float tm = fmaxf(fmaxf(s0,s1), fmaxf(s2,s3));
            tm = fmaxf(tm, __shfl_xor(tm, 1));
            tm = fmaxf(tm, __shfl_xor(tm, 2));
            tm = fmaxf(tm, __shfl_xor(tm, 4));
            float mo = mrow[r];
            float mnew = fmaxf(mo, tm);
            float f = __expf(mo - mnew);
            float e0 = __expf(s0 - mnew), e1 = __expf(s1 - mnew);
            float e2 = __expf(s2 - mnew), e3 = __expf(s3 - mnew);
            float ssum = e0+e1+e2+e3;
            ssum += __shfl_xor(ssum, 1);
            ssum += __shfl_xor(ssum, 2);
            ssum += __shfl_xor(ssum, 4);
            if (seg == 0) {
                mrow[r] = mnew;
                lrow[r] = lrow[r]*f + ssum;
                frow[r] = f;
            }
            ushort4 pw;
            pw.x = f2bf(e0); pw.y = f2bf(e1); pw.z = f2bf(e2); pw.w = f2bf(e3);
            *reinterpret_cast<ushort4*>(&Pb[r*PSTR + jl]) = pw;
        }
        __syncthreads();

        // ---- PV: rescale O, then accumulate P @ V with V frags direct from global ----
        {
            float f0 = frow[rw+0], f1 = frow[rw+1], f2 = frow[rw+2], f3 = frow[rw+3];
#pragma unroll
            for (int nn=0;nn<2;nn++) {
                Oa[nn][0] *= f0; Oa[nn][1] *= f1; Oa[nn][2] *= f2; Oa[nn][3] *= f3;
            }
            bf16x8 pf = *reinterpret_cast<const bf16x8*>(&Pb[(mi*16 + l15)*PSTR + kc]);
            const unsigned short* vb = heads + 1024 + n*64;
#pragma unroll
            for (int nn=0;nn<2;nn++) {
                int d = (half*2+nn)*16 + l15;
                bf16x8 vf;
#pragma unroll
                for (int e=0;e<8;e++) {
                    int gj = j0 + kc + e; if (gj > S_LEN-1) gj = S_LEN-1;
                    vf[e] = (short)vb[(size_t)(gj*BATCH_N + b)*1536 + d];
                }
                Oa[nn] = __builtin_amdgcn_mfma_f32_16x16x32_bf16(pf, vf, Oa[nn], 0,0,0);
            }
        }
    }
    __syncthreads();

    // ---- epilogue ----
    {
        float linv[4];
#pragma unroll
        for (int r=0;r<4;r++) linv[r] = 1.0f / lrow[rw+r];
#pragma unroll
        for (int nn=0;nn<2;nn++) {
            int d = (half*2+nn)*16 + l15;
#pragma unroll
            for (int r=0;r<4;r++) {
                int gi = i0 + rw + r;
                if (gi < S_LEN)
                    av[(size_t)(gi*BATCH_N + b)*DMODEL + n*64 + d] = f2bf(Oa[nn][r]*linv[r]);
            }
        }
    }
}

// ---------------- final classifier (f32) ----------------
__global__ __launch_bounds__(64) void final_kernel(
    const float* __restrict__ core, const float* __restrict__ fcw,
    const float* __restrict__ fcb, float* __restrict__ out)
{
    int idx = blockIdx.x;
    int b = idx / 10, c = idx % 10;
    int lane = threadIdx.x;
    const float* row = &core[(size_t)((S_LEN-1)*BATCH_N + b)*DMODEL];
    float acc = 0.f;
    for (int d = lane; d < DMODEL; d += 64)
        acc = fmaf(row[d], fcw[d*10 + c], acc);
#pragma unroll
    for (int off = 32; off; off >>= 1) acc += __shfl_xor(acc, off);
    if (lane == 0) out[b*10 + c] = acc + fcb[c];
}

extern "C" void kernel_launch(void* const* d_in, const int* in_sizes, int n_in,
                              void* d_out, int out_size, void* d_ws, size_t ws_size,
                              hipStream_t stream)
{
    const float* sig   = (const float*)d_in[0];
    const float* cw    = (const float*)d_in[1];
    const float* cb    = (const float*)d_in[2];
    const float* qkv_w = (const float*)d_in[3];
    const float* r_w   = (const float*)d_in[4];
    const float* o_w   = (const float*)d_in[5];
    const float* ff1_w = (const float*)d_in[6];
    const float* ff1_b = (const float*)d_in[7];
    const float* ff2_w = (const float*)d_in[8];
    const float* ff2_b = (const float*)d_in[9];
    const float* rwb   = (const float*)d_in[10];
    const float* rrb   = (const float*)d_in[11];
    const float* fcw   = (const float*)d_in[12];
    const float* fcb   = (const float*)d_in[13];
    float* out = (float*)d_out;

    // workspace layout
    float* core = (float*)d_ws;                                    // 4092*512 f32
    unsigned short* core_bf = (unsigned short*)(core + (size_t)MROWS*DMODEL);
    unsigned short* pe_bf   = core_bf + (size_t)MROWS*DMODEL;      // 2045*512
    unsigned short* rk_bf   = pe_bf   + (size_t)RLEN*DMODEL;       // 2045*512
    unsigned short* av_bf   = rk_bf   + (size_t)RLEN*DMODEL;       // 4092*512
    unsigned short* big_bf  = av_bf   + (size_t)MROWS*DMODEL;      // 4092*2048
    unsigned short* qkvT = big_bf + (size_t)MROWS*DINNER;          // 1536*512
    unsigned short* rwT  = qkvT + (size_t)(3*DMODEL)*DMODEL;       // 512*512
    unsigned short* owT  = rwT  + (size_t)DMODEL*DMODEL;           // 512*512
    unsigned short* ff1T = owT  + (size_t)DMODEL*DMODEL;           // 2048*512
    unsigned short* ff2T = ff1T + (size_t)DINNER*DMODEL;           // 512*2048

    conv_pool_kernel<<<dim3(S_LEN, BATCH_N), 512, 0, stream>>>(sig, cw, cb, core, core_bf);
    posemb_kernel<<<RLEN, 512, 0, stream>>>(pe_bf);

    for (int l = 0; l < NLAYER; l++) {
        transpose_cvt_kernel<<<dim3(48,16), 256, 0, stream>>>(
            qkv_w + (size_t)l*DMODEL*(3*DMODEL), qkvT, DMODEL, 3*DMODEL);
        transpose_cvt_kernel<<<dim3(16,16), 256, 0, stream>>>(
            r_w + (size_t)l*DMODEL*DMODEL, rwT, DMODEL, DMODEL);
        transpose_cvt_kernel<<<dim3(16,16), 256, 0, stream>>>(
            o_w + (size_t)l*DMODEL*DMODEL, owT, DMODEL, DMODEL);
        transpose_cvt_kernel<<<dim3(64,16), 256, 0, stream>>>(
            ff1_w + (size_t)l*DMODEL*DINNER, ff1T, DMODEL, DINNER);
        transpose_cvt_kernel<<<dim3(16,64), 256, 0, stream>>>(
            ff2_w + (size_t)l*DINNER*DMODEL, ff2T, DINNER, DMODEL);

        // heads = core @ qkv_w -> bf16
        gemm_mfma<128,false,false,false,false,true><<<dim3(12,32), 256, 0, stream>>>(
            core_bf, qkvT, nullptr, nullptr, big_bf, MROWS, 3*DMODEL, DMODEL);
        // rk = pe @ r_w -> bf16
        gemm_mfma<64,false,false,false,false,true><<<dim3(8,16), 256, 0, stream>>>(
            pe_bf, rwT, nullptr, nullptr, rk_bf, RLEN, DMODEL, DMODEL);
        // attention
        attn_mfma_kernel<<<dim3(32,32), 256, 0, stream>>>(big_bf, rk_bf, rwb, rrb, av_bf);
        // core += av @ o_w  (f32 + bf16 mirror)
        gemm_mfma<64,true,false,false,true,true><<<dim3(8,32), 256, 0, stream>>>(
            av_bf, owT, nullptr, core, core_bf, MROWS, DMODEL, DMODEL);
        // hid = relu(core @ ff1 + b) -> bf16
        gemm_mfma<128,false,true,true,false,true><<<dim3(16,32), 256, 0, stream>>>(
            core_bf, ff1T, ff1_b + (size_t)l*DINNER, nullptr, big_bf, MROWS, DINNER, DMODEL);
        // core += hid @ ff2 + b  (f32 + bf16 mirror)
        gemm_mfma<64,true,true,false,true,true><<<dim3(8,32), 256, 0, stream>>>(
            big_bf, ff2T, ff2_b + (size_t)l*DMODEL, core, core_bf, MROWS, DMODEL, DINNER);
    }

    final_kernel<<<40, 64, 0, stream>>>(core, fcw, fcb, out);
}